// Round 8
// baseline (187.790 us; speedup 1.0000x reference)
//
#include <hip/hip_runtime.h>
#include <math.h>

typedef unsigned short u16;
typedef unsigned int   u32;

#define OUTSZ 7
#define B_ 2
#define C_ 256
#define R_ 256
#define N_ (B_ * R_)

// NHWC bf16 scratch: pixel index -> 256 bf16 channels (512B records).
// per-batch level pixel bases: L0:0 L1:80000 L2:100000 L3:105000 (b-major within level)
#define PX_TOTAL 106250
#define WS_NEEDED ((size_t)PX_TOTAL * 256 * 2)

__device__ __forceinline__ u16 f2bf(float v) {
    u32 u = __float_as_uint(v);
    u += 0x7fffu + ((u >> 16) & 1u);           // RNE to bf16
    return (u16)(u >> 16);
}

__device__ __forceinline__ u32 pack2bf(float a, float b) {
    return (u32)f2bf(a) | ((u32)f2bf(b) << 16);
}

// ---------------- NCHW fp32 -> NHWC bf16 v2: full-record blocks, dense writes ----
// R7 conclusion: three different cast structures all plateau ~53us/2.1TB/s;
// line-level efficiency is clean, so the suspect is DRAM-row density: each
// 512B record was assembled by 4 blocks (cb 0..3) executing us apart -> the
// HBM write stream of any one block is 128B-per-512B sparse. v2: one block
// owns ALL 256 channels of 64 pixels -> writes one dense contiguous 32KB
// span; consecutive blocks write adjacent spans. Reads: 256 rows x 256B
// (2 full lines/row; adjacent tiles fetch adjacent chunks).
// LDS [64px][128u32] unpadded, chunk-XOR swizzle pc = c ^ (px&7):
//   b128 reads granule-uniform (R5-class pattern, measured 0 conflicts),
//   b32 pack-writes spread ~<=2 lanes/bank.
// grid = (832 tiles, 2 batches), block 512. Tail/odd tiles -> scalar path.
__global__ __launch_bounds__(512) void nhwc_cast(
    const float* __restrict__ f0, const float* __restrict__ f1,
    const float* __restrict__ f2, const float* __restrict__ f3,
    u16* __restrict__ dst)
{
    __shared__ u32 sm[64 * 128];   // 32 KB
    const int tid = threadIdx.x;

    const int t = blockIdx.x;      // 0..831 px-tile
    const int b = blockIdx.y;
    const float* src; int HWsz, dstBase, ft;
    if      (t < 625) { src = f0; HWsz = 40000; dstBase = 0;      ft = t;       }
    else if (t < 782) { src = f1; HWsz = 10000; dstBase = 80000;  ft = t - 625; }
    else if (t < 822) { src = f2; HWsz = 2500;  dstBase = 100000; ft = t - 782; }
    else              { src = f3; HWsz = 625;   dstBase = 105000; ft = t - 822; }

    const int px0 = ft * 64;
    const int rem = HWsz - px0;                // 1..64
    const int p   = tid >> 2;                  // channel pair 0..127 (ch 2p, 2p+1)
    const int qb  = tid & 3;

    const float* r0 = src + (size_t)(b * C_ + 2 * p) * HWsz + px0;
    const float* r1 = r0 + HWsz;
    const bool vec = ((HWsz & 3) == 0) && (rem >= 64);

    if (vec) {
        #pragma unroll
        for (int i = 0; i < 4; ++i) {
            const int q = i * 4 + qb;          // px quad 0..15
            float4 v0 = *(const float4*)(r0 + 4 * q);
            float4 v1 = *(const float4*)(r1 + 4 * q);
            #pragma unroll
            for (int j = 0; j < 4; ++j) {
                const int px = 4 * q + j;
                const int idx = px * 128 + (((p >> 2) ^ (px & 7)) << 2) + (p & 3);
                float a = j == 0 ? v0.x : j == 1 ? v0.y : j == 2 ? v0.z : v0.w;
                float c = j == 0 ? v1.x : j == 1 ? v1.y : j == 2 ? v1.z : v1.w;
                sm[idx] = pack2bf(a, c);
            }
        }
    } else {
        #pragma unroll
        for (int i = 0; i < 4; ++i) {
            const int q = i * 4 + qb;
            #pragma unroll
            for (int j = 0; j < 4; ++j) {
                const int px = 4 * q + j;
                float a = (px < rem) ? r0[px] : 0.0f;
                float c = (px < rem) ? r1[px] : 0.0f;
                const int idx = px * 128 + (((p >> 2) ^ (px & 7)) << 2) + (p & 3);
                sm[idx] = pack2bf(a, c);
            }
        }
    }
    __syncthreads();

    // store: thread (px = tid>>3, sub = tid&7); 4 iterations cover the 32
    // 16B-chunks of each 512B record; 8 lanes/chunk-group = 128B contiguous,
    // block = dense 32KB span.
    const int px  = tid >> 3;                  // 0..63
    const int sub = tid & 7;
    if (px < rem) {
        u16* rec = dst + (size_t)(dstBase + b * HWsz + px0 + px) * 256;
        const u32* row = &sm[px * 128];
        #pragma unroll
        for (int i = 0; i < 4; ++i) {
            const int c  = i * 8 + sub;                    // logical chunk 0..31
            const int pc = c ^ (px & 7);                   // swizzled chunk
            uint4 o = *(const uint4*)&row[pc << 2];
            *(uint4*)(rec + (c << 3)) = o;
        }
    }
}

// ---------------- gather: block owns (ROI n, 128 channels); prep fused in-block ----
// 512 threads / 8 waves, cells strided by 8. u32-per-lane record loads,
// LDS-staged output, block writes one contiguous 25KB slab as full-line
// float4s. Bilinear tables computed by threads 0..27. (unchanged from R6)
__global__ __launch_bounds__(512, 8) void roi_gather(
    const u16* __restrict__ ws16, const float* __restrict__ boxes,
    float* __restrict__ out)
{
    __shared__ float lds[128 * 49];            // 25088 B
    __shared__ float s_wy0[14], s_wy1[14], s_wx0[14], s_wx1[14];
    __shared__ int   s_yl[14], s_yh[14], s_xl[14], s_xh[14];
    __shared__ int   s_base, s_W;

    const int g    = blockIdx.x;
    const int n    = blockIdx.y;
    const int tid  = threadIdx.x;
    const int lane = tid & 63;
    const int wave = tid >> 6;     // 0..7

    // ---- fused prep: threads 0..13 -> y entries, 14..27 -> x entries ----
    if (tid < 28) {
        const float* bx = boxes + (size_t)n * 4;
        float x1 = bx[0], y1 = bx[1], x2 = bx[2], y2 = bx[3];
        float area = (x2 - x1) * (y2 - y1);
        float lf = floorf(4.0f + log2f(sqrtf(area) / 224.0f + 1e-8f));
        lf = fminf(fmaxf(lf, 2.0f), 5.0f);
        int lvl = (int)lf - 2;
        const float scales[4] = {0.25f, 0.125f, 0.0625f, 0.03125f};
        const int   sizes[4]  = {200, 100, 50, 25};
        const int   bases[4]  = {0, 80000, 100000, 105000};
        float scale = scales[lvl];
        int   HW    = sizes[lvl];
        float lim = (float)HW, cap = lim - 1.0f;
        float fx1 = x1 * scale, fy1 = y1 * scale;
        float bw = fmaxf(x2 * scale - fx1, 1.0f) / (float)OUTSZ;
        float bh = fmaxf(y2 * scale - fy1, 1.0f) / (float)OUTSZ;
        if (tid == 0) { s_base = bases[lvl] + (n >> 8) * HW * HW; s_W = HW; }

        const int  i   = (tid < 14) ? tid : tid - 14;
        const bool isy = tid < 14;
        float o  = isy ? fy1 : fx1;
        float st = isy ? bh  : bw;
        float gq = (float)(i >> 1) + ((float)(i & 1) + 0.5f) * 0.5f;
        float c = o + st * gq;
        bool  v = (c > -1.0f) && (c < lim);
        float cc = fmaxf(c, 0.0f);
        float low = floorf(cc);
        bool  edge = low >= cap;
        low = fminf(low, cap);
        float high = fminf(low + 1.0f, cap);
        float fr = edge ? 0.0f : (cc - low);
        float w0 = v ? (1.0f - fr) : 0.0f;
        float w1 = v ? fr : 0.0f;
        if (isy) { s_yl[i] = (int)low; s_yh[i] = (int)high; s_wy0[i] = w0; s_wy1[i] = w1; }
        else     { s_xl[i] = (int)low; s_xh[i] = (int)high; s_wx0[i] = w0; s_wx1[i] = w1; }
    }
    __syncthreads();

    const int base = s_base, W = s_W;
    const int c0 = g * 128;

    for (int cell = wave; cell < 49; cell += 8) {
        const int cu = __builtin_amdgcn_readfirstlane(cell);
        const int oy = cu / 7, ox = cu - oy * 7;
        float a0 = 0.0f, a1 = 0.0f;
        #pragma unroll
        for (int sy = 0; sy < 2; ++sy) {
            const int ei = oy * 2 + sy;
            const float wy0 = s_wy0[ei], wy1 = s_wy1[ei];
            const int rl = base + s_yl[ei] * W;
            const int rh = base + s_yh[ei] * W;
            #pragma unroll
            for (int sx = 0; sx < 2; ++sx) {
                const int ej = ox * 2 + sx;
                const float w00 = wy0 * s_wx0[ej], w01 = wy0 * s_wx1[ej];
                const float w10 = wy1 * s_wx0[ej], w11 = wy1 * s_wx1[ej];
                const int xl = s_xl[ej], xh = s_xh[ej];
                u32 u00 = ((const u32*)(ws16 + (size_t)(rl + xl) * 256 + c0))[lane];
                u32 u01 = ((const u32*)(ws16 + (size_t)(rl + xh) * 256 + c0))[lane];
                u32 u10 = ((const u32*)(ws16 + (size_t)(rh + xl) * 256 + c0))[lane];
                u32 u11 = ((const u32*)(ws16 + (size_t)(rh + xh) * 256 + c0))[lane];
                a0 += w00 * __uint_as_float(u00 << 16) + w01 * __uint_as_float(u01 << 16)
                    + w10 * __uint_as_float(u10 << 16) + w11 * __uint_as_float(u11 << 16);
                a1 += w00 * __uint_as_float(u00 & 0xffff0000u) + w01 * __uint_as_float(u01 & 0xffff0000u)
                    + w10 * __uint_as_float(u10 & 0xffff0000u) + w11 * __uint_as_float(u11 & 0xffff0000u);
            }
        }
        lds[(2 * lane) * 49 + cu]     = a0 * 0.25f;
        lds[(2 * lane + 1) * 49 + cu] = a1 * 0.25f;
    }
    __syncthreads();

    const float4* lv = (const float4*)lds;
    float4* ov = (float4*)(out + ((size_t)(n * C_ + c0)) * 49);
    for (int i = tid; i < 1568; i += 512) ov[i] = lv[i];
}

// ---------------- fallback: direct gather (if ws too small) ----------------
__global__ __launch_bounds__(256) void roi_direct(
    const float* __restrict__ f0, const float* __restrict__ f1,
    const float* __restrict__ f2, const float* __restrict__ f3,
    const float* __restrict__ boxes, float* __restrict__ out)
{
    const int total = B_ * R_ * C_ * OUTSZ * OUTSZ;
    int idx = blockIdx.x * blockDim.x + threadIdx.x;
    if (idx >= total) return;
    int ox = idx % 7, oy = (idx / 7) % 7, c = (idx / 49) % C_, n = idx / (49 * C_), b = n >> 8;
    const float* bx = boxes + (size_t)n * 4;
    float x1 = bx[0], y1 = bx[1], x2 = bx[2], y2 = bx[3];
    float lf = floorf(4.0f + log2f(sqrtf((x2 - x1) * (y2 - y1)) / 224.0f + 1e-8f));
    int lvl = (int)fminf(fmaxf(lf, 2.0f), 5.0f) - 2;
    const float scales[4] = {0.25f, 0.125f, 0.0625f, 0.03125f};
    const int sizes[4] = {200, 100, 50, 25};
    float scale = scales[lvl]; int HW = sizes[lvl];
    const float* fl = lvl == 0 ? f0 : lvl == 1 ? f1 : lvl == 2 ? f2 : f3;
    float fx1 = x1 * scale, fy1 = y1 * scale;
    float bw = fmaxf(x2 * scale - fx1, 1.0f) / 7.0f, bh = fmaxf(y2 * scale - fy1, 1.0f) / 7.0f;
    const float* plane = fl + ((size_t)(b * C_ + c)) * HW * HW;
    float lim = (float)HW, cap = lim - 1.0f, acc = 0.0f;
    #pragma unroll
    for (int sy = 0; sy < 2; sy++) {
        float yc = fy1 + bh * ((float)oy + ((float)sy + 0.5f) * 0.5f);
        bool vy = (yc > -1.0f) && (yc < lim);
        float ccy = fmaxf(yc, 0.0f), lowy = floorf(ccy);
        bool ey = lowy >= cap; lowy = fminf(lowy, cap);
        float highy = fminf(lowy + 1.0f, cap);
        float wfy = ey ? 0.0f : (ccy - lowy);
        int yl = (int)lowy, yh = (int)highy;
        #pragma unroll
        for (int sx = 0; sx < 2; sx++) {
            float xc = fx1 + bw * ((float)ox + ((float)sx + 0.5f) * 0.5f);
            bool vx = (xc > -1.0f) && (xc < lim);
            float ccx = fmaxf(xc, 0.0f), lowx = floorf(ccx);
            bool ex = lowx >= cap; lowx = fminf(lowx, cap);
            float highx = fminf(lowx + 1.0f, cap);
            float wfx = ex ? 0.0f : (ccx - lowx);
            int xl = (int)lowx, xh = (int)highx;
            if (vy && vx) {
                float v00 = plane[yl * HW + xl], v01 = plane[yl * HW + xh];
                float v10 = plane[yh * HW + xl], v11 = plane[yh * HW + xh];
                acc += (1.0f - wfy) * ((1.0f - wfx) * v00 + wfx * v01)
                     + wfy * ((1.0f - wfx) * v10 + wfx * v11);
            }
        }
    }
    out[idx] = acc * 0.25f;
}

extern "C" void kernel_launch(void* const* d_in, const int* in_sizes, int n_in,
                              void* d_out, int out_size, void* d_ws, size_t ws_size,
                              hipStream_t stream) {
    const float* f0    = (const float*)d_in[0];
    const float* f1    = (const float*)d_in[1];
    const float* f2    = (const float*)d_in[2];
    const float* f3    = (const float*)d_in[3];
    const float* boxes = (const float*)d_in[4];
    float* out = (float*)d_out;

    if (ws_size < WS_NEEDED) {
        const int total = B_ * R_ * C_ * OUTSZ * OUTSZ;
        roi_direct<<<(total + 255) / 256, 256, 0, stream>>>(f0, f1, f2, f3, boxes, out);
        return;
    }

    u16* nhwc = (u16*)d_ws;

    nhwc_cast<<<dim3(832, 2), 512, 0, stream>>>(f0, f1, f2, f3, nhwc);
    roi_gather<<<dim3(2, N_), 512, 0, stream>>>(nhwc, boxes, out);
}

// Round 9
// 180.521 us; speedup vs baseline: 1.0403x; 1.0403x over previous
//
#include <hip/hip_runtime.h>
#include <math.h>

typedef unsigned short u16;
typedef unsigned int   u32;

#define OUTSZ 7
#define B_ 2
#define C_ 256
#define R_ 256
#define N_ (B_ * R_)

// NHWC bf16 scratch: pixel index -> 256 bf16 channels (512B records).
// per-batch level pixel bases: L0:0 L1:80000 L2:100000 L3:105000 (b-major within level)
#define PX_TOTAL 106250
#define WS_NEEDED ((size_t)PX_TOTAL * 256 * 2)

__device__ __forceinline__ u16 f2bf(float v) {
    u32 u = __float_as_uint(v);
    u += 0x7fffu + ((u >> 16) & 1u);           // RNE to bf16
    return (u16)(u >> 16);
}

__device__ __forceinline__ u32 pack2bf(float a, float b) {
    return (u32)f2bf(a) | ((u32)f2bf(b) << 16);
}

__device__ __forceinline__ float bflo(u32 u) { return __uint_as_float(u << 16); }
__device__ __forceinline__ float bfhi(u32 u) { return __uint_as_float(u & 0xffff0000u); }

// ---------------- NCHW fp32 -> NHWC bf16: R5 structure (best measured: 52us) ----
// 512 threads (8 waves); wave owns 8 consecutive channels. 8 float4 row loads,
// pack bf16 uint4 in regs, px-major swizzled LDS (q = wave ^ (lane&7),
// conflict-free b128), store full 128B-line segments (8 lanes x 16B / px).
// grid = (210 px-tiles, 4 ch-blocks, 2 batches), block 512.
__global__ __launch_bounds__(512, 8) void nhwc_cast(
    const float* __restrict__ f0, const float* __restrict__ f1,
    const float* __restrict__ f2, const float* __restrict__ f3,
    u16* __restrict__ dst)
{
    __shared__ u32 lds32[256 * 32];   // 32 KB: px-major, 8 uint4-quads per px, swizzled
    const int tid  = threadIdx.x;
    const int lane = tid & 63;
    const int wave = tid >> 6;        // 0..7

    const int t  = blockIdx.x;
    const int cb = blockIdx.y;
    const int b  = blockIdx.z;
    const float* src; int HWsz, dstBase, ft;
    if      (t < 157) { src = f0; HWsz = 40000; dstBase = 0;      ft = t;       }
    else if (t < 197) { src = f1; HWsz = 10000; dstBase = 80000;  ft = t - 157; }
    else if (t < 207) { src = f2; HWsz = 2500;  dstBase = 100000; ft = t - 197; }
    else              { src = f3; HWsz = 625;   dstBase = 105000; ft = t - 207; }

    const int fbase = ft * 256;
    const int cw    = cb * 64 + wave * 8;        // this wave's 8-channel base
    const int rem   = HWsz - fbase;              // >= 1
    const int p0    = 4 * lane;
    const bool vec  = ((HWsz & 3) == 0) && (p0 + 3 < rem);

    const float* base = src + ((size_t)(b * C_ + cw)) * HWsz + fbase;

    float f[8][4];
    #pragma unroll
    for (int i = 0; i < 8; ++i) {
        const float* row = base + (size_t)i * HWsz;
        if (vec) {
            float4 v = *(const float4*)(row + p0);
            f[i][0] = v.x; f[i][1] = v.y; f[i][2] = v.z; f[i][3] = v.w;
        } else {
            #pragma unroll
            for (int k = 0; k < 4; ++k)
                f[i][k] = (p0 + k < rem) ? row[p0 + k] : 0.0f;
        }
    }

    #pragma unroll
    for (int j = 0; j < 4; ++j) {
        uint4 o;
        o.x = pack2bf(f[0][j], f[1][j]);
        o.y = pack2bf(f[2][j], f[3][j]);
        o.z = pack2bf(f[4][j], f[5][j]);
        o.w = pack2bf(f[6][j], f[7][j]);
        const int q = wave ^ (lane & 7);         // ((px>>2)&7) == lane&7
        *(uint4*)&lds32[(p0 + j) * 32 + q * 4] = o;
    }
    __syncthreads();

    const int maxpx = rem < 256 ? rem : 256;
    #pragma unroll
    for (int i = 0; i < 4; ++i) {
        const int idx = i * 512 + tid;
        const int px  = idx >> 3;
        const int sub = idx & 7;
        if (px < maxpx) {
            const int q = sub ^ ((px >> 2) & 7);
            uint4 o = *(const uint4*)&lds32[px * 32 + q * 4];
            *(uint4*)(dst + (size_t)(dstBase + b * HWsz + fbase + px) * 256 + cb * 64 + sub * 8) = o;
        }
    }
}

// ---------------- gather v2: x-pair 1KB loads, one block per ROI (256 ch) ----
// Bilinear x-neighbors are ADJACENT 512B records -> one uint4-per-lane wave
// load (1KB) fetches BOTH: lanes 0-31 = record xl (weight wlo), lanes 32-63 =
// record xl+1 (weight whi). Edge collapse xh==xl rebased to pair (xl-1, xl)
// with weights (0, wx0+wx1) -- identical algebra, always in-bounds. Halves
// folded with one shfl_xor(32) per acc reg. Wave-load instrs per ROI:
// 1568 -> 392 (4x), granule 256B -> 1KB. 52KB LDS -> 3 blocks/CU, 24 waves.
// grid = (N_), block 512; wave handles whole cells (stride 8).
__global__ __launch_bounds__(512) void roi_gather(
    const u16* __restrict__ ws16, const float* __restrict__ boxes,
    float* __restrict__ out)
{
    __shared__ float ldsO[49 * 264];           // cell-major, 256ch + 8 pad (51.7KB)
    __shared__ float s_wy0[14], s_wy1[14], s_wlo[14], s_whi[14];
    __shared__ int   s_yl[14], s_yh[14], s_xo[14];
    __shared__ int   s_base, s_W;

    const int n    = blockIdx.x;
    const int tid  = threadIdx.x;
    const int lane = tid & 63;
    const int wave = tid >> 6;     // 0..7

    // ---- fused prep: threads 0..13 -> y entries, 14..27 -> x entries ----
    if (tid < 28) {
        const float* bx = boxes + (size_t)n * 4;
        float x1 = bx[0], y1 = bx[1], x2 = bx[2], y2 = bx[3];
        float area = (x2 - x1) * (y2 - y1);
        float lf = floorf(4.0f + log2f(sqrtf(area) / 224.0f + 1e-8f));
        lf = fminf(fmaxf(lf, 2.0f), 5.0f);
        int lvl = (int)lf - 2;
        const float scales[4] = {0.25f, 0.125f, 0.0625f, 0.03125f};
        const int   sizes[4]  = {200, 100, 50, 25};
        const int   bases[4]  = {0, 80000, 100000, 105000};
        float scale = scales[lvl];
        int   HW    = sizes[lvl];
        float lim = (float)HW, cap = lim - 1.0f;
        float fx1 = x1 * scale, fy1 = y1 * scale;
        float bw = fmaxf(x2 * scale - fx1, 1.0f) / (float)OUTSZ;
        float bh = fmaxf(y2 * scale - fy1, 1.0f) / (float)OUTSZ;
        if (tid == 0) { s_base = bases[lvl] + (n >> 8) * HW * HW; s_W = HW; }

        const int  i   = (tid < 14) ? tid : tid - 14;
        const bool isy = tid < 14;
        float o  = isy ? fy1 : fx1;
        float st = isy ? bh  : bw;
        float gq = (float)(i >> 1) + ((float)(i & 1) + 0.5f) * 0.5f;
        float c = o + st * gq;
        bool  v = (c > -1.0f) && (c < lim);
        float cc = fmaxf(c, 0.0f);
        float low = floorf(cc);
        bool  edge = low >= cap;
        low = fminf(low, cap);
        float high = fminf(low + 1.0f, cap);
        float fr = edge ? 0.0f : (cc - low);
        float w0 = v ? (1.0f - fr) : 0.0f;
        float w1 = v ? fr : 0.0f;
        if (isy) {
            s_yl[i] = (int)low; s_yh[i] = (int)high; s_wy0[i] = w0; s_wy1[i] = w1;
        } else {
            int xl = (int)low, xh = (int)high;
            bool col = (xh == xl);               // only at xl == cap (>= 24)
            s_xo[i]  = col ? xl - 1 : xl;
            s_wlo[i] = col ? 0.0f : w0;
            s_whi[i] = col ? (w0 + w1) : w1;
        }
    }
    __syncthreads();

    const int base = s_base, W = s_W;
    const bool hiHalf = lane >= 32;

    for (int cell = wave; cell < 49; cell += 8) {
        const int cu = __builtin_amdgcn_readfirstlane(cell);
        const int oy = cu / 7, ox = cu - oy * 7;
        float a0 = 0, a1 = 0, a2 = 0, a3 = 0, a4 = 0, a5 = 0, a6 = 0, a7 = 0;
        #pragma unroll
        for (int sy = 0; sy < 2; ++sy) {
            const int ei = oy * 2 + sy;
            const float wy0 = s_wy0[ei], wy1 = s_wy1[ei];
            const size_t rl = (size_t)(base + s_yl[ei] * W);
            const size_t rh = (size_t)(base + s_yh[ei] * W);
            #pragma unroll
            for (int sx = 0; sx < 2; ++sx) {
                const int ej = ox * 2 + sx;
                const int xo = s_xo[ej];
                const float wsel = hiHalf ? s_whi[ej] : s_wlo[ej];
                uint4 A = ((const uint4*)(ws16 + (rl + xo) * 256))[lane];
                const float wa = wy0 * wsel;
                a0 += wa * bflo(A.x); a1 += wa * bfhi(A.x);
                a2 += wa * bflo(A.y); a3 += wa * bfhi(A.y);
                a4 += wa * bflo(A.z); a5 += wa * bfhi(A.z);
                a6 += wa * bflo(A.w); a7 += wa * bfhi(A.w);
                uint4 Bv = ((const uint4*)(ws16 + (rh + xo) * 256))[lane];
                const float wb = wy1 * wsel;
                a0 += wb * bflo(Bv.x); a1 += wb * bfhi(Bv.x);
                a2 += wb * bflo(Bv.y); a3 += wb * bfhi(Bv.y);
                a4 += wb * bflo(Bv.z); a5 += wb * bfhi(Bv.z);
                a6 += wb * bflo(Bv.w); a7 += wb * bfhi(Bv.w);
            }
        }
        // fold the xl/xh halves: lane l <-> lane l^32 hold the same 8 channels
        a0 += __shfl_xor(a0, 32); a1 += __shfl_xor(a1, 32);
        a2 += __shfl_xor(a2, 32); a3 += __shfl_xor(a3, 32);
        a4 += __shfl_xor(a4, 32); a5 += __shfl_xor(a5, 32);
        a6 += __shfl_xor(a6, 32); a7 += __shfl_xor(a7, 32);
        // lane<32 stores ch 8l..8l+3; lane>=32 stores ch 8(l-32)+4..+7
        float* dstl = &ldsO[cu * 264 + (lane & 31) * 8 + (hiHalf ? 4 : 0)];
        float4 v = hiHalf ? make_float4(a4 * 0.25f, a5 * 0.25f, a6 * 0.25f, a7 * 0.25f)
                          : make_float4(a0 * 0.25f, a1 * 0.25f, a2 * 0.25f, a3 * 0.25f);
        *(float4*)dstl = v;
    }
    __syncthreads();

    // transpose store: out[n*12544 + c*49 + cell] contiguous, 1KB per wave instr
    float* op = out + (size_t)n * (C_ * 49);
    for (int i4 = tid; i4 < 3136; i4 += 512) {
        const int e = 4 * i4;
        float4 v;
        {   int c = e / 49,      r = e - 49 * c;          v.x = ldsO[r * 264 + c]; }
        {   int c = (e+1) / 49,  r = (e+1) - 49 * c;      v.y = ldsO[r * 264 + c]; }
        {   int c = (e+2) / 49,  r = (e+2) - 49 * c;      v.z = ldsO[r * 264 + c]; }
        {   int c = (e+3) / 49,  r = (e+3) - 49 * c;      v.w = ldsO[r * 264 + c]; }
        *(float4*)(op + e) = v;
    }
}

// ---------------- fallback: direct gather (if ws too small) ----------------
__global__ __launch_bounds__(256) void roi_direct(
    const float* __restrict__ f0, const float* __restrict__ f1,
    const float* __restrict__ f2, const float* __restrict__ f3,
    const float* __restrict__ boxes, float* __restrict__ out)
{
    const int total = B_ * R_ * C_ * OUTSZ * OUTSZ;
    int idx = blockIdx.x * blockDim.x + threadIdx.x;
    if (idx >= total) return;
    int ox = idx % 7, oy = (idx / 7) % 7, c = (idx / 49) % C_, n = idx / (49 * C_), b = n >> 8;
    const float* bx = boxes + (size_t)n * 4;
    float x1 = bx[0], y1 = bx[1], x2 = bx[2], y2 = bx[3];
    float lf = floorf(4.0f + log2f(sqrtf((x2 - x1) * (y2 - y1)) / 224.0f + 1e-8f));
    int lvl = (int)fminf(fmaxf(lf, 2.0f), 5.0f) - 2;
    const float scales[4] = {0.25f, 0.125f, 0.0625f, 0.03125f};
    const int sizes[4] = {200, 100, 50, 25};
    float scale = scales[lvl]; int HW = sizes[lvl];
    const float* fl = lvl == 0 ? f0 : lvl == 1 ? f1 : lvl == 2 ? f2 : f3;
    float fx1 = x1 * scale, fy1 = y1 * scale;
    float bw = fmaxf(x2 * scale - fx1, 1.0f) / 7.0f, bh = fmaxf(y2 * scale - fy1, 1.0f) / 7.0f;
    const float* plane = fl + ((size_t)(b * C_ + c)) * HW * HW;
    float lim = (float)HW, cap = lim - 1.0f, acc = 0.0f;
    #pragma unroll
    for (int sy = 0; sy < 2; sy++) {
        float yc = fy1 + bh * ((float)oy + ((float)sy + 0.5f) * 0.5f);
        bool vy = (yc > -1.0f) && (yc < lim);
        float ccy = fmaxf(yc, 0.0f), lowy = floorf(ccy);
        bool ey = lowy >= cap; lowy = fminf(lowy, cap);
        float highy = fminf(lowy + 1.0f, cap);
        float wfy = ey ? 0.0f : (ccy - lowy);
        int yl = (int)lowy, yh = (int)highy;
        #pragma unroll
        for (int sx = 0; sx < 2; sx++) {
            float xc = fx1 + bw * ((float)ox + ((float)sx + 0.5f) * 0.5f);
            bool vx = (xc > -1.0f) && (xc < lim);
            float ccx = fmaxf(xc, 0.0f), lowx = floorf(ccx);
            bool ex = lowx >= cap; lowx = fminf(lowx, cap);
            float highx = fminf(lowx + 1.0f, cap);
            float wfx = ex ? 0.0f : (ccx - lowx);
            int xl = (int)lowx, xh = (int)highx;
            if (vy && vx) {
                float v00 = plane[yl * HW + xl], v01 = plane[yl * HW + xh];
                float v10 = plane[yh * HW + xl], v11 = plane[yh * HW + xh];
                acc += (1.0f - wfy) * ((1.0f - wfx) * v00 + wfx * v01)
                     + wfy * ((1.0f - wfx) * v10 + wfx * v11);
            }
        }
    }
    out[idx] = acc * 0.25f;
}

extern "C" void kernel_launch(void* const* d_in, const int* in_sizes, int n_in,
                              void* d_out, int out_size, void* d_ws, size_t ws_size,
                              hipStream_t stream) {
    const float* f0    = (const float*)d_in[0];
    const float* f1    = (const float*)d_in[1];
    const float* f2    = (const float*)d_in[2];
    const float* f3    = (const float*)d_in[3];
    const float* boxes = (const float*)d_in[4];
    float* out = (float*)d_out;

    if (ws_size < WS_NEEDED) {
        const int total = B_ * R_ * C_ * OUTSZ * OUTSZ;
        roi_direct<<<(total + 255) / 256, 256, 0, stream>>>(f0, f1, f2, f3, boxes, out);
        return;
    }

    u16* nhwc = (u16*)d_ws;

    nhwc_cast<<<dim3(210, 4, 2), 512, 0, stream>>>(f0, f1, f2, f3, nhwc);
    roi_gather<<<dim3(N_), 512, 0, stream>>>(nhwc, boxes, out);
}

// Round 10
// 180.319 us; speedup vs baseline: 1.0414x; 1.0011x over previous
//
#include <hip/hip_runtime.h>
#include <math.h>

typedef unsigned short u16;
typedef unsigned int   u32;

#define OUTSZ 7
#define B_ 2
#define C_ 256
#define R_ 256
#define N_ (B_ * R_)

// NHWC bf16 scratch: pixel index -> 256 bf16 channels (512B records).
// per-batch level pixel bases: L0:0 L1:80000 L2:100000 L3:105000 (b-major within level)
#define PX_TOTAL 106250
#define WS_NEEDED ((size_t)PX_TOTAL * 256 * 2)

__device__ __forceinline__ u16 f2bf(float v) {
    u32 u = __float_as_uint(v);
    u += 0x7fffu + ((u >> 16) & 1u);           // RNE to bf16
    return (u16)(u >> 16);
}

__device__ __forceinline__ u32 pack2bf(float a, float b) {
    return (u32)f2bf(a) | ((u32)f2bf(b) << 16);
}

__device__ __forceinline__ float bflo(u32 u) { return __uint_as_float(u << 16); }
__device__ __forceinline__ float bfhi(u32 u) { return __uint_as_float(u & 0xffff0000u); }

// ---------------- NCHW fp32 -> NHWC bf16: R5 structure (measured floor 52-53us) ----
// [UNCHANGED from R9] 512 threads; wave owns 8 ch; 8 float4 row loads; pack in
// regs; px-major swizzled LDS (conflict-free b128); full 128B-line stores.
__global__ __launch_bounds__(512, 8) void nhwc_cast(
    const float* __restrict__ f0, const float* __restrict__ f1,
    const float* __restrict__ f2, const float* __restrict__ f3,
    u16* __restrict__ dst)
{
    __shared__ u32 lds32[256 * 32];   // 32 KB
    const int tid  = threadIdx.x;
    const int lane = tid & 63;
    const int wave = tid >> 6;

    const int t  = blockIdx.x;
    const int cb = blockIdx.y;
    const int b  = blockIdx.z;
    const float* src; int HWsz, dstBase, ft;
    if      (t < 157) { src = f0; HWsz = 40000; dstBase = 0;      ft = t;       }
    else if (t < 197) { src = f1; HWsz = 10000; dstBase = 80000;  ft = t - 157; }
    else if (t < 207) { src = f2; HWsz = 2500;  dstBase = 100000; ft = t - 197; }
    else              { src = f3; HWsz = 625;   dstBase = 105000; ft = t - 207; }

    const int fbase = ft * 256;
    const int cw    = cb * 64 + wave * 8;
    const int rem   = HWsz - fbase;
    const int p0    = 4 * lane;
    const bool vec  = ((HWsz & 3) == 0) && (p0 + 3 < rem);

    const float* base = src + ((size_t)(b * C_ + cw)) * HWsz + fbase;

    float f[8][4];
    #pragma unroll
    for (int i = 0; i < 8; ++i) {
        const float* row = base + (size_t)i * HWsz;
        if (vec) {
            float4 v = *(const float4*)(row + p0);
            f[i][0] = v.x; f[i][1] = v.y; f[i][2] = v.z; f[i][3] = v.w;
        } else {
            #pragma unroll
            for (int k = 0; k < 4; ++k)
                f[i][k] = (p0 + k < rem) ? row[p0 + k] : 0.0f;
        }
    }

    #pragma unroll
    for (int j = 0; j < 4; ++j) {
        uint4 o;
        o.x = pack2bf(f[0][j], f[1][j]);
        o.y = pack2bf(f[2][j], f[3][j]);
        o.z = pack2bf(f[4][j], f[5][j]);
        o.w = pack2bf(f[6][j], f[7][j]);
        const int q = wave ^ (lane & 7);
        *(uint4*)&lds32[(p0 + j) * 32 + q * 4] = o;
    }
    __syncthreads();

    const int maxpx = rem < 256 ? rem : 256;
    #pragma unroll
    for (int i = 0; i < 4; ++i) {
        const int idx = i * 512 + tid;
        const int px  = idx >> 3;
        const int sub = idx & 7;
        if (px < maxpx) {
            const int q = sub ^ ((px >> 2) & 7);
            uint4 o = *(const uint4*)&lds32[px * 32 + q * 4];
            *(uint4*)(dst + (size_t)(dstBase + b * HWsz + fbase + px) * 256 + cb * 64 + sub * 8) = o;
        }
    }
}

// ---------------- gather v3: x-pair loads x channel-split (full occupancy) ----
// v2's verified x-pair algebra (lanes 0-31 = record xo / wlo, lanes 32-63 =
// record xo+1 / whi; edge collapse rebased to (xl-1, xl), weights (0,w0+w1))
// combined with R6's 128-ch split: uint2/lane covers the 256B g-half of each
// record (2 x 256B segments / instr). 26KB LDS + 512 thr -> 4 blocks/CU =
// 32 waves/CU (100% vs v2's 50%): TLP for a latency-bound scatter.
// grid = (2, N_), block 512.
__global__ __launch_bounds__(512, 8) void roi_gather(
    const u16* __restrict__ ws16, const float* __restrict__ boxes,
    float* __restrict__ out)
{
    __shared__ float ldsO[49 * 132];           // 25.9 KB: cell-major, 128ch + pad
    __shared__ float s_wy0[14], s_wy1[14], s_wlo[14], s_whi[14];
    __shared__ int   s_yl[14], s_yh[14], s_xo[14];
    __shared__ int   s_base, s_W;

    const int g    = blockIdx.x;   // channel half
    const int n    = blockIdx.y;
    const int tid  = threadIdx.x;
    const int lane = tid & 63;
    const int wave = tid >> 6;

    if (tid < 28) {
        const float* bx = boxes + (size_t)n * 4;
        float x1 = bx[0], y1 = bx[1], x2 = bx[2], y2 = bx[3];
        float area = (x2 - x1) * (y2 - y1);
        float lf = floorf(4.0f + log2f(sqrtf(area) / 224.0f + 1e-8f));
        lf = fminf(fmaxf(lf, 2.0f), 5.0f);
        int lvl = (int)lf - 2;
        const float scales[4] = {0.25f, 0.125f, 0.0625f, 0.03125f};
        const int   sizes[4]  = {200, 100, 50, 25};
        const int   bases[4]  = {0, 80000, 100000, 105000};
        float scale = scales[lvl];
        int   HW    = sizes[lvl];
        float lim = (float)HW, cap = lim - 1.0f;
        float fx1 = x1 * scale, fy1 = y1 * scale;
        float bw = fmaxf(x2 * scale - fx1, 1.0f) / (float)OUTSZ;
        float bh = fmaxf(y2 * scale - fy1, 1.0f) / (float)OUTSZ;
        if (tid == 0) { s_base = bases[lvl] + (n >> 8) * HW * HW; s_W = HW; }

        const int  i   = (tid < 14) ? tid : tid - 14;
        const bool isy = tid < 14;
        float o  = isy ? fy1 : fx1;
        float st = isy ? bh  : bw;
        float gq = (float)(i >> 1) + ((float)(i & 1) + 0.5f) * 0.5f;
        float c = o + st * gq;
        bool  v = (c > -1.0f) && (c < lim);
        float cc = fmaxf(c, 0.0f);
        float low = floorf(cc);
        bool  edge = low >= cap;
        low = fminf(low, cap);
        float high = fminf(low + 1.0f, cap);
        float fr = edge ? 0.0f : (cc - low);
        float w0 = v ? (1.0f - fr) : 0.0f;
        float w1 = v ? fr : 0.0f;
        if (isy) {
            s_yl[i] = (int)low; s_yh[i] = (int)high; s_wy0[i] = w0; s_wy1[i] = w1;
        } else {
            int xl = (int)low, xh = (int)high;
            bool col = (xh == xl);               // only at xl == cap (>= 24)
            s_xo[i]  = col ? xl - 1 : xl;
            s_wlo[i] = col ? 0.0f : w0;
            s_whi[i] = col ? (w0 + w1) : w1;
        }
    }
    __syncthreads();

    const int base = s_base, W = s_W;
    const int co   = g * 64;                   // u32 offset of g-half within record
    const bool hiHalf = lane >= 32;
    const int xsel = lane >> 5;                // 0: record xo, 1: record xo+1
    const int ck   = lane & 31;                // uint2 chunk within 256B half

    for (int cell = wave; cell < 49; cell += 8) {
        const int cu = __builtin_amdgcn_readfirstlane(cell);
        const int oy = cu / 7, ox = cu - oy * 7;
        float a0 = 0, a1 = 0, a2 = 0, a3 = 0;
        #pragma unroll
        for (int sy = 0; sy < 2; ++sy) {
            const int ei = oy * 2 + sy;
            const float wy0 = s_wy0[ei], wy1 = s_wy1[ei];
            const size_t rl = (size_t)(base + s_yl[ei] * W);
            const size_t rh = (size_t)(base + s_yh[ei] * W);
            #pragma unroll
            for (int sx = 0; sx < 2; ++sx) {
                const int ej = ox * 2 + sx;
                const int xo = s_xo[ej];
                const float wsel = hiHalf ? s_whi[ej] : s_wlo[ej];
                uint2 A = ((const uint2*)((const u32*)(ws16 + (rl + xo + xsel) * 256) + co))[ck];
                const float wa = wy0 * wsel;
                a0 += wa * bflo(A.x); a1 += wa * bfhi(A.x);
                a2 += wa * bflo(A.y); a3 += wa * bfhi(A.y);
                uint2 Bv = ((const uint2*)((const u32*)(ws16 + (rh + xo + xsel) * 256) + co))[ck];
                const float wb = wy1 * wsel;
                a0 += wb * bflo(Bv.x); a1 += wb * bfhi(Bv.x);
                a2 += wb * bflo(Bv.y); a3 += wb * bfhi(Bv.y);
            }
        }
        a0 += __shfl_xor(a0, 32); a1 += __shfl_xor(a1, 32);
        a2 += __shfl_xor(a2, 32); a3 += __shfl_xor(a3, 32);
        if (!hiHalf) {
            float4 v = make_float4(a0 * 0.25f, a1 * 0.25f, a2 * 0.25f, a3 * 0.25f);
            *(float4*)&ldsO[cu * 132 + ck * 4] = v;   // ch_local = ck*4..+3
        }
    }
    __syncthreads();

    // transpose store: slab out[n*12544 + g*6272 + c_local*49 + cell]
    float* op = out + (size_t)n * (C_ * 49) + g * (128 * 49);
    for (int i4 = tid; i4 < 1568; i4 += 512) {
        const int e = 4 * i4;
        int c0i = (e + 0) / 49, r0i = (e + 0) - 49 * c0i;
        int c1i = (e + 1) / 49, r1i = (e + 1) - 49 * c1i;
        int c2i = (e + 2) / 49, r2i = (e + 2) - 49 * c2i;
        int c3i = (e + 3) / 49, r3i = (e + 3) - 49 * c3i;
        float4 w;
        w.x = ldsO[r0i * 132 + c0i];
        w.y = ldsO[r1i * 132 + c1i];
        w.z = ldsO[r2i * 132 + c2i];
        w.w = ldsO[r3i * 132 + c3i];
        *(float4*)(op + e) = w;
    }
}

// ---------------- fallback: direct gather (if ws too small) ----------------
__global__ __launch_bounds__(256) void roi_direct(
    const float* __restrict__ f0, const float* __restrict__ f1,
    const float* __restrict__ f2, const float* __restrict__ f3,
    const float* __restrict__ boxes, float* __restrict__ out)
{
    const int total = B_ * R_ * C_ * OUTSZ * OUTSZ;
    int idx = blockIdx.x * blockDim.x + threadIdx.x;
    if (idx >= total) return;
    int ox = idx % 7, oy = (idx / 7) % 7, c = (idx / 49) % C_, n = idx / (49 * C_), b = n >> 8;
    const float* bx = boxes + (size_t)n * 4;
    float x1 = bx[0], y1 = bx[1], x2 = bx[2], y2 = bx[3];
    float lf = floorf(4.0f + log2f(sqrtf((x2 - x1) * (y2 - y1)) / 224.0f + 1e-8f));
    int lvl = (int)fminf(fmaxf(lf, 2.0f), 5.0f) - 2;
    const float scales[4] = {0.25f, 0.125f, 0.0625f, 0.03125f};
    const int sizes[4] = {200, 100, 50, 25};
    float scale = scales[lvl]; int HW = sizes[lvl];
    const float* fl = lvl == 0 ? f0 : lvl == 1 ? f1 : lvl == 2 ? f2 : f3;
    float fx1 = x1 * scale, fy1 = y1 * scale;
    float bw = fmaxf(x2 * scale - fx1, 1.0f) / 7.0f, bh = fmaxf(y2 * scale - fy1, 1.0f) / 7.0f;
    const float* plane = fl + ((size_t)(b * C_ + c)) * HW * HW;
    float lim = (float)HW, cap = lim - 1.0f, acc = 0.0f;
    #pragma unroll
    for (int sy = 0; sy < 2; sy++) {
        float yc = fy1 + bh * ((float)oy + ((float)sy + 0.5f) * 0.5f);
        bool vy = (yc > -1.0f) && (yc < lim);
        float ccy = fmaxf(yc, 0.0f), lowy = floorf(ccy);
        bool ey = lowy >= cap; lowy = fminf(lowy, cap);
        float highy = fminf(lowy + 1.0f, cap);
        float wfy = ey ? 0.0f : (ccy - lowy);
        int yl = (int)lowy, yh = (int)highy;
        #pragma unroll
        for (int sx = 0; sx < 2; sx++) {
            float xc = fx1 + bw * ((float)ox + ((float)sx + 0.5f) * 0.5f);
            bool vx = (xc > -1.0f) && (xc < lim);
            float ccx = fmaxf(xc, 0.0f), lowx = floorf(ccx);
            bool ex = lowx >= cap; lowx = fminf(lowx, cap);
            float highx = fminf(lowx + 1.0f, cap);
            float wfx = ex ? 0.0f : (ccx - lowx);
            int xl = (int)lowx, xh = (int)highx;
            if (vy && vx) {
                float v00 = plane[yl * HW + xl], v01 = plane[yl * HW + xh];
                float v10 = plane[yh * HW + xl], v11 = plane[yh * HW + xh];
                acc += (1.0f - wfy) * ((1.0f - wfx) * v00 + wfx * v01)
                     + wfy * ((1.0f - wfx) * v10 + wfx * v11);
            }
        }
    }
    out[idx] = acc * 0.25f;
}

extern "C" void kernel_launch(void* const* d_in, const int* in_sizes, int n_in,
                              void* d_out, int out_size, void* d_ws, size_t ws_size,
                              hipStream_t stream) {
    const float* f0    = (const float*)d_in[0];
    const float* f1    = (const float*)d_in[1];
    const float* f2    = (const float*)d_in[2];
    const float* f3    = (const float*)d_in[3];
    const float* boxes = (const float*)d_in[4];
    float* out = (float*)d_out;

    if (ws_size < WS_NEEDED) {
        const int total = B_ * R_ * C_ * OUTSZ * OUTSZ;
        roi_direct<<<(total + 255) / 256, 256, 0, stream>>>(f0, f1, f2, f3, boxes, out);
        return;
    }

    u16* nhwc = (u16*)d_ws;

    nhwc_cast<<<dim3(210, 4, 2), 512, 0, stream>>>(f0, f1, f2, f3, nhwc);
    roi_gather<<<dim3(2, N_), 512, 0, stream>>>(nhwc, boxes, out);
}